// Round 1
// baseline (543.489 us; speedup 1.0000x reference)
//
#include <hip/hip_runtime.h>

typedef unsigned short u16;
typedef __bf16 bf16x8 __attribute__((ext_vector_type(8)));
typedef float f32x4 __attribute__((ext_vector_type(4)));

// Problem constants: B=2, S=2048, D=2048, H=16, HD=128, F=3*H*HD=6144, M=B*S=4096

__device__ __forceinline__ u16 f2bf(float x) {
  __bf16 h = (__bf16)x;
  return __builtin_bit_cast(u16, h);
}
__device__ __forceinline__ float bf2f(u16 u) {
  unsigned int v = ((unsigned int)u) << 16;
  return __builtin_bit_cast(float, v);
}

// ---------------- cast fp32 -> bf16 (vectorized) ----------------
__global__ __launch_bounds__(256) void cast_f32_bf16(const float* __restrict__ src,
                                                     u16* __restrict__ dst, int n4) {
  int i = blockIdx.x * 256 + threadIdx.x;
  if (i >= n4) return;
  float4 v = ((const float4*)src)[i];
  ushort4 o;
  o.x = f2bf(v.x); o.y = f2bf(v.y); o.z = f2bf(v.z); o.w = f2bf(v.w);
  ((ushort4*)dst)[i] = o;
}

// ---------------- QKV projection GEMM ----------------
// C[m, f] = sum_d X[m,d] * W[f,d]   (both row-major, K-contiguous = B^T form)
// M=4096, N=6144, K=2048. Tile 128x128, BK=64, 256 threads (4 waves, 64x64 each).
// Epilogue scatters column block nb=blockIdx.y: which=nb%3 (0=q,1=k,2=v), h=nb/3, hd=col.
// Q,K written [B,H,S,HD]; V written transposed [B,H,HD,S].
__global__ __launch_bounds__(256) void gemm_qkv(const u16* __restrict__ A,
                                                const u16* __restrict__ W,
                                                u16* __restrict__ Qb,
                                                u16* __restrict__ Kb,
                                                u16* __restrict__ Vt) {
  __shared__ __align__(16) u16 As[128 * 72];  // rows padded 64->72 elems (2-way bank alias = free)
  __shared__ __align__(16) u16 Bs[128 * 72];
  const int tid = threadIdx.x;
  const int lane = tid & 63;
  const int wave = tid >> 6;
  const int wm = (wave >> 1) * 64;
  const int wn = (wave & 1) * 64;
  const int r16 = lane & 15;
  const int g4 = lane >> 4;
  const int bm = blockIdx.x * 128;
  const int bn = blockIdx.y * 128;

  f32x4 acc[4][4];
  f32x4 zero = {0.0f, 0.0f, 0.0f, 0.0f};
#pragma unroll
  for (int m = 0; m < 4; m++)
#pragma unroll
    for (int n = 0; n < 4; n++) acc[m][n] = zero;

  for (int kt = 0; kt < 2048; kt += 64) {
    __syncthreads();
#pragma unroll
    for (int i = 0; i < 4; i++) {
      int idx = tid + i * 256;        // 1024 x 16B chunks per tile
      int row = idx >> 3;             // 0..127
      int k8 = (idx & 7) * 8;         // 0..56
      *(uint4*)(&As[row * 72 + k8]) =
          *(const uint4*)(&A[(size_t)(bm + row) * 2048 + kt + k8]);
      *(uint4*)(&Bs[row * 72 + k8]) =
          *(const uint4*)(&W[(size_t)(bn + row) * 2048 + kt + k8]);
    }
    __syncthreads();
#pragma unroll
    for (int ks = 0; ks < 2; ks++) {
      bf16x8 af[4], bfr[4];
#pragma unroll
      for (int m = 0; m < 4; m++)
        af[m] = *(const bf16x8*)(&As[(wm + m * 16 + r16) * 72 + ks * 32 + g4 * 8]);
#pragma unroll
      for (int n = 0; n < 4; n++)
        bfr[n] = *(const bf16x8*)(&Bs[(wn + n * 16 + r16) * 72 + ks * 32 + g4 * 8]);
#pragma unroll
      for (int m = 0; m < 4; m++)
#pragma unroll
        for (int n = 0; n < 4; n++)
          acc[m][n] = __builtin_amdgcn_mfma_f32_16x16x32_bf16(af[m], bfr[n], acc[m][n], 0, 0, 0);
    }
  }

  const int which = blockIdx.y % 3;
  const int hh = blockIdx.y / 3;
#pragma unroll
  for (int m = 0; m < 4; m++) {
#pragma unroll
    for (int n = 0; n < 4; n++) {
#pragma unroll
      for (int r = 0; r < 4; r++) {
        // C/D layout (verified m89): col = lane&15, row = (lane>>4)*4 + r
        int row = bm + wm + m * 16 + g4 * 4 + r;   // global m index (b*S+s)
        int hd = wn + n * 16 + r16;                // 0..127 within the head third
        int bb = row >> 11;
        int s = row & 2047;
        size_t bhIdx = (size_t)(bb * 16 + hh);
        u16 o = f2bf(acc[m][n][r]);
        if (which == 2)
          Vt[(bhIdx * 128 + hd) * 2048 + s] = o;          // V transposed: [bh][hd][s]
        else if (which == 1)
          Kb[(bhIdx * 2048 + s) * 128 + hd] = o;          // [bh][s][hd]
        else
          Qb[(bhIdx * 2048 + s) * 128 + hd] = o;
      }
    }
  }
}

// ---------------- RoPE (in place, fp32 math) ----------------
// out[i]    = x[i]*cos[s,i]    - x[i+64]*sin[s,i]     (i < 64)
// out[i+64] = x[i+64]*cos[s,i] + x[i]*sin[s,i]        (cos/sin halves equal by construction)
__global__ __launch_bounds__(256) void rope_kernel(u16* __restrict__ Qb, u16* __restrict__ Kb,
                                                   const float* __restrict__ cosb,
                                                   const float* __restrict__ sinb) {
  int id = blockIdx.x * 256 + threadIdx.x;  // 2 tensors * 32 bh * 2048 s * 16 vec4 = 2,097,152
  int j = id & 15;
  int s = (id >> 4) & 2047;
  int bh = (id >> 15) & 31;
  int tt = id >> 20;
  u16* row = (tt ? Kb : Qb) + ((size_t)bh * 2048 + s) * 128;
  int i = j * 4;
  float4 c = *(const float4*)(cosb + s * 128 + i);
  float4 sn = *(const float4*)(sinb + s * 128 + i);
  ushort4 a = *(ushort4*)(row + i);
  ushort4 b = *(ushort4*)(row + 64 + i);
  float x10 = bf2f(a.x), x11 = bf2f(a.y), x12 = bf2f(a.z), x13 = bf2f(a.w);
  float x20 = bf2f(b.x), x21 = bf2f(b.y), x22 = bf2f(b.z), x23 = bf2f(b.w);
  ushort4 o1, o2;
  o1.x = f2bf(x10 * c.x - x20 * sn.x);
  o1.y = f2bf(x11 * c.y - x21 * sn.y);
  o1.z = f2bf(x12 * c.z - x22 * sn.z);
  o1.w = f2bf(x13 * c.w - x23 * sn.w);
  o2.x = f2bf(x20 * c.x + x10 * sn.x);
  o2.y = f2bf(x21 * c.y + x11 * sn.y);
  o2.z = f2bf(x22 * c.z + x12 * sn.z);
  o2.w = f2bf(x23 * c.w + x13 * sn.w);
  *(ushort4*)(row + i) = o1;
  *(ushort4*)(row + 64 + i) = o2;
}

// ---------------- Flash attention (causal, online softmax) ----------------
// Grid (S/64, B*H). 4 waves; wave w owns Q rows t*64+w*16 .. +15.
// Q frags in registers; K tile [64][128] and V^T tile [128][64] staged to LDS.
// P: C-layout -> bf16 -> per-wave LDS -> A-layout read (m120 pattern).
__global__ __launch_bounds__(256) void flash_attn(const u16* __restrict__ Q,
                                                  const u16* __restrict__ K,
                                                  const u16* __restrict__ Vt,
                                                  u16* __restrict__ O) {
  __shared__ __align__(16) u16 Ks[64 * 136];   // [key][hd], padded 128->136
  __shared__ __align__(16) u16 Vs[128 * 72];   // [hd][key], padded 64->72
  __shared__ __align__(16) u16 Ps[4 * 16 * 72];  // per-wave [qrow][key], padded
  const int tid = threadIdx.x;
  const int lane = tid & 63;
  const int wave = tid >> 6;
  const int t = blockIdx.x;
  const int bh = blockIdx.y;
  const int r16 = lane & 15;
  const int g4 = lane >> 4;
  const u16* Qh = Q + (size_t)bh * 2048 * 128;
  const u16* Kh = K + (size_t)bh * 2048 * 128;
  const u16* Vh = Vt + (size_t)bh * 128 * 2048;

  // Q fragments (A-layout: row = lane&15, k = (lane>>4)*8 + j), 4 k-steps of 32
  bf16x8 qf[4];
  {
    int qrow = t * 64 + wave * 16 + r16;
#pragma unroll
    for (int ks = 0; ks < 4; ks++)
      qf[ks] = *(const bf16x8*)(Qh + (size_t)qrow * 128 + ks * 32 + g4 * 8);
  }

  f32x4 o[8];
  f32x4 zero = {0.0f, 0.0f, 0.0f, 0.0f};
#pragma unroll
  for (int c = 0; c < 8; c++) o[c] = zero;
  float m_i[4], l_i[4];
#pragma unroll
  for (int r = 0; r < 4; r++) { m_i[r] = -__builtin_inff(); l_i[r] = 0.0f; }

  const float sc = 0.08838834764831845f * 1.4426950408889634f;  // 1/sqrt(128) * log2(e)

  for (int u = 0; u <= t; u++) {
    __syncthreads();
#pragma unroll
    for (int i = 0; i < 4; i++) {  // stage K tile: 64 rows x 128 hd
      int idx = tid + i * 256;
      int row = idx >> 4;
      int k8 = (idx & 15) * 8;
      *(uint4*)(&Ks[row * 136 + k8]) =
          *(const uint4*)(&Kh[(size_t)(u * 64 + row) * 128 + k8]);
    }
#pragma unroll
    for (int i = 0; i < 4; i++) {  // stage V^T tile: 128 hd x 64 keys
      int idx = tid + i * 256;
      int hd = idx >> 3;
      int k8 = (idx & 7) * 8;
      *(uint4*)(&Vs[hd * 72 + k8]) =
          *(const uint4*)(&Vh[(size_t)hd * 2048 + u * 64 + k8]);
    }
    __syncthreads();

    // S = Q K^T for this wave's 16 rows x 64 keys
    f32x4 sacc[4];
#pragma unroll
    for (int n = 0; n < 4; n++) sacc[n] = zero;
#pragma unroll
    for (int n = 0; n < 4; n++) {
#pragma unroll
      for (int ks = 0; ks < 4; ks++) {
        bf16x8 kf = *(const bf16x8*)(&Ks[(n * 16 + r16) * 136 + ks * 32 + g4 * 8]);
        sacc[n] = __builtin_amdgcn_mfma_f32_16x16x32_bf16(qf[ks], kf, sacc[n], 0, 0, 0);
      }
    }

    // online softmax (base-2). Lane holds rows g4*4+r, col n*16+r16.
    float p[4][4];   // [n][r]
    float alpha[4];
#pragma unroll
    for (int r = 0; r < 4; r++) {
      int rowg = t * 64 + wave * 16 + g4 * 4 + r;
      float e[4];
#pragma unroll
      for (int n = 0; n < 4; n++) {
        e[n] = sacc[n][r] * sc;
        if (u == t) {
          int key = u * 64 + n * 16 + r16;
          if (key > rowg) e[n] = -__builtin_inff();
        }
      }
      float mr = fmaxf(fmaxf(e[0], e[1]), fmaxf(e[2], e[3]));
      mr = fmaxf(mr, __shfl_xor(mr, 1));
      mr = fmaxf(mr, __shfl_xor(mr, 2));
      mr = fmaxf(mr, __shfl_xor(mr, 4));
      mr = fmaxf(mr, __shfl_xor(mr, 8));
      float mn = fmaxf(m_i[r], mr);
      alpha[r] = exp2f(m_i[r] - mn);
      m_i[r] = mn;
      float srow = 0.0f;
#pragma unroll
      for (int n = 0; n < 4; n++) {
        float pv = exp2f(e[n] - mn);
        p[n][r] = pv;
        srow += pv;
      }
      srow += __shfl_xor(srow, 1);
      srow += __shfl_xor(srow, 2);
      srow += __shfl_xor(srow, 4);
      srow += __shfl_xor(srow, 8);
      l_i[r] = l_i[r] * alpha[r] + srow;
    }
#pragma unroll
    for (int c = 0; c < 8; c++)
#pragma unroll
      for (int r = 0; r < 4; r++) o[c][r] *= alpha[r];

    // P: C-layout -> per-wave LDS (bf16)
    u16* Pw = &Ps[wave * 16 * 72];
#pragma unroll
    for (int n = 0; n < 4; n++)
#pragma unroll
      for (int r = 0; r < 4; r++)
        Pw[(g4 * 4 + r) * 72 + n * 16 + r16] = f2bf(p[n][r]);

    // PV: O[16 x 128] += P[16 x 64] * V[64 x 128]
#pragma unroll
    for (int ks2 = 0; ks2 < 2; ks2++) {
      bf16x8 pf = *(const bf16x8*)(&Pw[r16 * 72 + ks2 * 32 + g4 * 8]);
#pragma unroll
      for (int c = 0; c < 8; c++) {
        bf16x8 vf = *(const bf16x8*)(&Vs[(c * 16 + r16) * 72 + ks2 * 32 + g4 * 8]);
        o[c] = __builtin_amdgcn_mfma_f32_16x16x32_bf16(pf, vf, o[c], 0, 0, 0);
      }
    }
  }

  // epilogue: O /= l, write [B,S,H,HD] bf16
  const int b = bh >> 4;
  const int h = bh & 15;
  float rl[4];
#pragma unroll
  for (int r = 0; r < 4; r++) rl[r] = 1.0f / l_i[r];
#pragma unroll
  for (int c = 0; c < 8; c++) {
#pragma unroll
    for (int r = 0; r < 4; r++) {
      int rowg = t * 64 + wave * 16 + g4 * 4 + r;
      int col = c * 16 + r16;
      O[((size_t)(b * 2048 + rowg)) * 2048 + h * 128 + col] = f2bf(o[c][r] * rl[r]);
    }
  }
}

// ---------------- Output projection GEMM ----------------
// out[m, d] = sum_f Attn[m,f] * Wo[d,f].  M=4096, N=2048, K=2048. fp32 output.
__global__ __launch_bounds__(256) void gemm_out(const u16* __restrict__ A,
                                                const u16* __restrict__ W,
                                                float* __restrict__ out) {
  __shared__ __align__(16) u16 As[128 * 72];
  __shared__ __align__(16) u16 Bs[128 * 72];
  const int tid = threadIdx.x;
  const int lane = tid & 63;
  const int wave = tid >> 6;
  const int wm = (wave >> 1) * 64;
  const int wn = (wave & 1) * 64;
  const int r16 = lane & 15;
  const int g4 = lane >> 4;
  const int bm = blockIdx.x * 128;
  const int bn = blockIdx.y * 128;

  f32x4 acc[4][4];
  f32x4 zero = {0.0f, 0.0f, 0.0f, 0.0f};
#pragma unroll
  for (int m = 0; m < 4; m++)
#pragma unroll
    for (int n = 0; n < 4; n++) acc[m][n] = zero;

  for (int kt = 0; kt < 2048; kt += 64) {
    __syncthreads();
#pragma unroll
    for (int i = 0; i < 4; i++) {
      int idx = tid + i * 256;
      int row = idx >> 3;
      int k8 = (idx & 7) * 8;
      *(uint4*)(&As[row * 72 + k8]) =
          *(const uint4*)(&A[(size_t)(bm + row) * 2048 + kt + k8]);
      *(uint4*)(&Bs[row * 72 + k8]) =
          *(const uint4*)(&W[(size_t)(bn + row) * 2048 + kt + k8]);
    }
    __syncthreads();
#pragma unroll
    for (int ks = 0; ks < 2; ks++) {
      bf16x8 af[4], bfr[4];
#pragma unroll
      for (int m = 0; m < 4; m++)
        af[m] = *(const bf16x8*)(&As[(wm + m * 16 + r16) * 72 + ks * 32 + g4 * 8]);
#pragma unroll
      for (int n = 0; n < 4; n++)
        bfr[n] = *(const bf16x8*)(&Bs[(wn + n * 16 + r16) * 72 + ks * 32 + g4 * 8]);
#pragma unroll
      for (int m = 0; m < 4; m++)
#pragma unroll
        for (int n = 0; n < 4; n++)
          acc[m][n] = __builtin_amdgcn_mfma_f32_16x16x32_bf16(af[m], bfr[n], acc[m][n], 0, 0, 0);
    }
  }

#pragma unroll
  for (int m = 0; m < 4; m++) {
#pragma unroll
    for (int n = 0; n < 4; n++) {
#pragma unroll
      for (int r = 0; r < 4; r++) {
        int row = bm + wm + m * 16 + g4 * 4 + r;
        int col = bn + wn + n * 16 + r16;
        out[(size_t)row * 2048 + col] = acc[m][n][r];
      }
    }
  }
}

extern "C" void kernel_launch(void* const* d_in, const int* in_sizes, int n_in,
                              void* d_out, int out_size, void* d_ws, size_t ws_size,
                              hipStream_t stream) {
  const float* hidden = (const float*)d_in[0];  // [2,2048,2048]
  const float* cosb   = (const float*)d_in[1];  // [2048,128]
  const float* sinb   = (const float*)d_in[2];  // [2048,128]
  const float* w_qkv  = (const float*)d_in[3];  // [3,2048,2048] -> flat [6144,2048]
  const float* w_o    = (const float*)d_in[4];  // [2048,2048]
  float* out = (float*)d_out;                   // [2,2048,2048] fp32

  char* ws = (char*)d_ws;
  u16* Xbf    = (u16*)(ws);                 // 4096*2048   bf16 = 16 MiB
  u16* Wqkvbf = (u16*)(ws + 16777216);      // 6144*2048         = 24 MiB
  u16* Wobf   = (u16*)(ws + 41943040);      // 2048*2048         = 8 MiB
  u16* Qb     = (u16*)(ws + 50331648);      // [B,H,S,HD]        = 16 MiB
  u16* Kb     = (u16*)(ws + 67108864);      // [B,H,S,HD]        = 16 MiB
  u16* Vt     = (u16*)(ws + 83886080);      // [B,H,HD,S]        = 16 MiB
  u16* Ob     = (u16*)(ws + 100663296);     // [B,S,H,HD]        = 16 MiB  (end 112 MiB)

  cast_f32_bf16<<<8192, 256, 0, stream>>>(hidden, Xbf, 2097152);
  cast_f32_bf16<<<12288, 256, 0, stream>>>(w_qkv, Wqkvbf, 3145728);
  cast_f32_bf16<<<4096, 256, 0, stream>>>(w_o, Wobf, 1048576);
  gemm_qkv<<<dim3(32, 48), 256, 0, stream>>>(Xbf, Wqkvbf, Qb, Kb, Vt);
  rope_kernel<<<8192, 256, 0, stream>>>(Qb, Kb, cosb, sinb);
  flash_attn<<<dim3(32, 32), 256, 0, stream>>>(Qb, Kb, Vt, Ob);
  gemm_out<<<dim3(32, 16), 256, 0, stream>>>(Ob, Wobf, out);
}

// Round 2
// 445.323 us; speedup vs baseline: 1.2204x; 1.2204x over previous
//
#include <hip/hip_runtime.h>

typedef unsigned short u16;
typedef __bf16 bf16x8 __attribute__((ext_vector_type(8)));
typedef float f32x4 __attribute__((ext_vector_type(4)));

// Problem constants: B=2, S=2048, D=2048, H=16, HD=128, F=3*H*HD=6144, M=B*S=4096

__device__ __forceinline__ u16 f2bf(float x) {
  __bf16 h = (__bf16)x;
  return __builtin_bit_cast(u16, h);
}
__device__ __forceinline__ float bf2f(u16 u) {
  unsigned int v = ((unsigned int)u) << 16;
  return __builtin_bit_cast(float, v);
}

// async global->LDS, 16B per lane. LDS dest = wave-uniform base + lane*16.
__device__ __forceinline__ void async_copy16(void* lds, const void* g) {
  __builtin_amdgcn_global_load_lds((const __attribute__((address_space(1))) void*)g,
                                   (__attribute__((address_space(3))) void*)lds, 16, 0, 0);
}

// ---------------- cast fp32 -> bf16 (vectorized) ----------------
__global__ __launch_bounds__(256) void cast_f32_bf16(const float* __restrict__ src,
                                                     u16* __restrict__ dst, int n4) {
  int i = blockIdx.x * 256 + threadIdx.x;
  if (i >= n4) return;
  float4 v = ((const float4*)src)[i];
  ushort4 o;
  o.x = f2bf(v.x); o.y = f2bf(v.y); o.z = f2bf(v.z); o.w = f2bf(v.w);
  ((ushort4*)dst)[i] = o;
}

// ---------------- QKV projection GEMM ----------------
// C[m,f] = sum_d X[m,d] * W[f,d]. M=4096, N=6144, K=2048. Tile 128x128, BK=64.
// LDS tiles [128][64] bf16, UNPADDED (global_load_lds requires lane-order layout);
// bank conflicts broken by 16B-chunk XOR swizzle: slot = chunk ^ (row&7).
__global__ __launch_bounds__(256) void gemm_qkv(const u16* __restrict__ A,
                                                const u16* __restrict__ W,
                                                u16* __restrict__ Qb,
                                                u16* __restrict__ Kb,
                                                u16* __restrict__ Vt) {
  __shared__ __align__(16) u16 As[128 * 64];
  __shared__ __align__(16) u16 Bs[128 * 64];
  const int tid = threadIdx.x;
  const int lane = tid & 63;
  const int wave = tid >> 6;
  const int wm = (wave >> 1) * 64;
  const int wn = (wave & 1) * 64;
  const int r16 = lane & 15;
  const int g4 = lane >> 4;
  const int rsw = r16 & 7;
  const int bm = blockIdx.x * 128;
  const int bn = blockIdx.y * 128;

  // staging map (constant over k): issue i covers rows wave*32+i*8 .. +7
  size_t aoff[4], boff[4];
  u16* ldsA[4];
  u16* ldsB[4];
#pragma unroll
  for (int i = 0; i < 4; i++) {
    int row = wave * 32 + i * 8 + (lane >> 3);
    int c = (lane & 7) ^ (row & 7);  // global chunk for this lane's LDS slot
    aoff[i] = (size_t)(bm + row) * 2048 + c * 8;
    boff[i] = (size_t)(bn + row) * 2048 + c * 8;
    ldsA[i] = &As[(wave * 4 + i) * 512];
    ldsB[i] = &Bs[(wave * 4 + i) * 512];
  }

  f32x4 acc[4][4];
  f32x4 zero = {0.0f, 0.0f, 0.0f, 0.0f};
#pragma unroll
  for (int m = 0; m < 4; m++)
#pragma unroll
    for (int n = 0; n < 4; n++) acc[m][n] = zero;

  for (int kt = 0; kt < 2048; kt += 64) {
    __syncthreads();
#pragma unroll
    for (int i = 0; i < 4; i++) {
      async_copy16(ldsA[i], A + aoff[i] + kt);
      async_copy16(ldsB[i], W + boff[i] + kt);
    }
    __syncthreads();
#pragma unroll
    for (int ks = 0; ks < 2; ks++) {
      bf16x8 af[4], bfr[4];
#pragma unroll
      for (int m = 0; m < 4; m++)
        af[m] = *(const bf16x8*)(&As[(wm + m * 16 + r16) * 64 + ((ks * 4 + g4) ^ rsw) * 8]);
#pragma unroll
      for (int n = 0; n < 4; n++)
        bfr[n] = *(const bf16x8*)(&Bs[(wn + n * 16 + r16) * 64 + ((ks * 4 + g4) ^ rsw) * 8]);
#pragma unroll
      for (int m = 0; m < 4; m++)
#pragma unroll
        for (int n = 0; n < 4; n++)
          acc[m][n] = __builtin_amdgcn_mfma_f32_16x16x32_bf16(af[m], bfr[n], acc[m][n], 0, 0, 0);
    }
  }

  const int which = blockIdx.y % 3;
  const int hh = blockIdx.y / 3;
#pragma unroll
  for (int m = 0; m < 4; m++) {
#pragma unroll
    for (int n = 0; n < 4; n++) {
#pragma unroll
      for (int r = 0; r < 4; r++) {
        // C/D layout (m89): col = lane&15, row = (lane>>4)*4 + r
        int row = bm + wm + m * 16 + g4 * 4 + r;   // global m index (b*S+s)
        int hd = wn + n * 16 + r16;                // 0..127 within the head third
        int bb = row >> 11;
        int s = row & 2047;
        size_t bhIdx = (size_t)(bb * 16 + hh);
        u16 o = f2bf(acc[m][n][r]);
        if (which == 2)
          Vt[(bhIdx * 128 + hd) * 2048 + s] = o;          // V transposed: [bh][hd][s]
        else if (which == 1)
          Kb[(bhIdx * 2048 + s) * 128 + hd] = o;          // [bh][s][hd]
        else
          Qb[(bhIdx * 2048 + s) * 128 + hd] = o;
      }
    }
  }
}

// ---------------- RoPE (in place, fp32 math) ----------------
__global__ __launch_bounds__(256) void rope_kernel(u16* __restrict__ Qb, u16* __restrict__ Kb,
                                                   const float* __restrict__ cosb,
                                                   const float* __restrict__ sinb) {
  int id = blockIdx.x * 256 + threadIdx.x;  // 2 * 32 bh * 2048 s * 16 vec4
  int j = id & 15;
  int s = (id >> 4) & 2047;
  int bh = (id >> 15) & 31;
  int tt = id >> 20;
  u16* row = (tt ? Kb : Qb) + ((size_t)bh * 2048 + s) * 128;
  int i = j * 4;
  float4 c = *(const float4*)(cosb + s * 128 + i);
  float4 sn = *(const float4*)(sinb + s * 128 + i);
  ushort4 a = *(ushort4*)(row + i);
  ushort4 b = *(ushort4*)(row + 64 + i);
  float x10 = bf2f(a.x), x11 = bf2f(a.y), x12 = bf2f(a.z), x13 = bf2f(a.w);
  float x20 = bf2f(b.x), x21 = bf2f(b.y), x22 = bf2f(b.z), x23 = bf2f(b.w);
  ushort4 o1, o2;
  o1.x = f2bf(x10 * c.x - x20 * sn.x);
  o1.y = f2bf(x11 * c.y - x21 * sn.y);
  o1.z = f2bf(x12 * c.z - x22 * sn.z);
  o1.w = f2bf(x13 * c.w - x23 * sn.w);
  o2.x = f2bf(x20 * c.x + x10 * sn.x);
  o2.y = f2bf(x21 * c.y + x11 * sn.y);
  o2.z = f2bf(x22 * c.z + x12 * sn.z);
  o2.w = f2bf(x23 * c.w + x13 * sn.w);
  *(ushort4*)(row + i) = o1;
  *(ushort4*)(row + 64 + i) = o2;
}

// ---------------- Flash attention (causal, online softmax) ----------------
// Grid (16, B*H). Block x processes q-tiles t=x and t=31-x (uniform 33 key-tiles).
// K [64][128] and V^T [128][64] staged via global_load_lds, XOR-swizzled.
__global__ __launch_bounds__(256) void flash_attn(const u16* __restrict__ Q,
                                                  const u16* __restrict__ K,
                                                  const u16* __restrict__ Vt,
                                                  u16* __restrict__ O) {
  __shared__ __align__(16) u16 Ks[64 * 128];   // [key][hd], swizzled 16B chunks
  __shared__ __align__(16) u16 Vs[128 * 64];   // [hd][key], swizzled 16B chunks
  __shared__ __align__(16) u16 Ps[4 * 16 * 72];  // per-wave [qrow][key], padded
  const int tid = threadIdx.x;
  const int lane = tid & 63;
  const int wave = tid >> 6;
  const int bh = blockIdx.y;
  const int r16 = lane & 15;
  const int g4 = lane >> 4;
  const int rsw = r16 & 7;
  const u16* Qh = Q + (size_t)bh * 2048 * 128;
  const u16* Kh = K + (size_t)bh * 2048 * 128;
  const u16* Vh = Vt + (size_t)bh * 128 * 2048;
  const int b = bh >> 4;
  const int h = bh & 15;

  // staging maps (constant): K tile rows = keys (16 chunks/row), V tile rows = hd (8 chunks/row)
  int krow = (wave * 4 + 0) * 4 + (lane >> 4);          // recomputed per issue below
  size_t koff[4], voff[4];
  u16* ldsK[4];
  u16* ldsV[4];
#pragma unroll
  for (int i = 0; i < 4; i++) {
    int kr = (wave * 4 + i) * 4 + (lane >> 4);          // 0..63
    int kc = (lane & 15) ^ (kr & 7);                    // chunk 0..15
    koff[i] = (size_t)kr * 128 + kc * 8;
    ldsK[i] = &Ks[(wave * 4 + i) * 512];
    int vr = (wave * 4 + i) * 8 + (lane >> 3);          // 0..127
    int vc = (lane & 7) ^ (vr & 7);
    voff[i] = (size_t)vr * 2048 + vc * 8;
    ldsV[i] = &Vs[(wave * 4 + i) * 512];
  }
  (void)krow;

  const float sc = 0.08838834764831845f * 1.4426950408889634f;  // 1/sqrt(128) * log2(e)

#pragma unroll 1
  for (int pass = 0; pass < 2; pass++) {
    const int t = pass == 0 ? (int)blockIdx.x : 31 - (int)blockIdx.x;

    bf16x8 qf[4];
    {
      int qrow = t * 64 + wave * 16 + r16;
#pragma unroll
      for (int ks = 0; ks < 4; ks++)
        qf[ks] = *(const bf16x8*)(Qh + (size_t)qrow * 128 + ks * 32 + g4 * 8);
    }

    f32x4 o[8];
    f32x4 zero = {0.0f, 0.0f, 0.0f, 0.0f};
#pragma unroll
    for (int c = 0; c < 8; c++) o[c] = zero;
    float m_i[4], l_i[4];
#pragma unroll
    for (int r = 0; r < 4; r++) { m_i[r] = -__builtin_inff(); l_i[r] = 0.0f; }

    for (int u = 0; u <= t; u++) {
      __syncthreads();
#pragma unroll
      for (int i = 0; i < 4; i++) {
        async_copy16(ldsK[i], Kh + (size_t)u * 64 * 128 + koff[i]);
        async_copy16(ldsV[i], Vh + (size_t)u * 64 + voff[i]);
      }
      __syncthreads();

      // S = Q K^T for this wave's 16 rows x 64 keys
      f32x4 sacc[4];
#pragma unroll
      for (int n = 0; n < 4; n++) sacc[n] = zero;
#pragma unroll
      for (int n = 0; n < 4; n++) {
#pragma unroll
        for (int ks = 0; ks < 4; ks++) {
          bf16x8 kf = *(const bf16x8*)(&Ks[(n * 16 + r16) * 128 + ((ks * 4 + g4) ^ rsw) * 8]);
          sacc[n] = __builtin_amdgcn_mfma_f32_16x16x32_bf16(qf[ks], kf, sacc[n], 0, 0, 0);
        }
      }

      // online softmax (base-2). Lane holds rows g4*4+r, col n*16+r16.
      float p[4][4];
      float alpha[4];
#pragma unroll
      for (int r = 0; r < 4; r++) {
        int rowg = t * 64 + wave * 16 + g4 * 4 + r;
        float e[4];
#pragma unroll
        for (int n = 0; n < 4; n++) {
          e[n] = sacc[n][r] * sc;
          if (u == t) {
            int key = u * 64 + n * 16 + r16;
            if (key > rowg) e[n] = -__builtin_inff();
          }
        }
        float mr = fmaxf(fmaxf(e[0], e[1]), fmaxf(e[2], e[3]));
        mr = fmaxf(mr, __shfl_xor(mr, 1));
        mr = fmaxf(mr, __shfl_xor(mr, 2));
        mr = fmaxf(mr, __shfl_xor(mr, 4));
        mr = fmaxf(mr, __shfl_xor(mr, 8));
        float mn = fmaxf(m_i[r], mr);
        alpha[r] = exp2f(m_i[r] - mn);
        m_i[r] = mn;
        float srow = 0.0f;
#pragma unroll
        for (int n = 0; n < 4; n++) {
          float pv = exp2f(e[n] - mn);
          p[n][r] = pv;
          srow += pv;
        }
        srow += __shfl_xor(srow, 1);
        srow += __shfl_xor(srow, 2);
        srow += __shfl_xor(srow, 4);
        srow += __shfl_xor(srow, 8);
        l_i[r] = l_i[r] * alpha[r] + srow;
      }
#pragma unroll
      for (int c = 0; c < 8; c++)
#pragma unroll
        for (int r = 0; r < 4; r++) o[c][r] *= alpha[r];

      // P: C-layout -> per-wave LDS (bf16)
      u16* Pw = &Ps[wave * 16 * 72];
#pragma unroll
      for (int n = 0; n < 4; n++)
#pragma unroll
        for (int r = 0; r < 4; r++)
          Pw[(g4 * 4 + r) * 72 + n * 16 + r16] = f2bf(p[n][r]);

      // PV: O[16 x 128] += P[16 x 64] * V[64 x 128]
#pragma unroll
      for (int ks2 = 0; ks2 < 2; ks2++) {
        bf16x8 pf = *(const bf16x8*)(&Pw[r16 * 72 + ks2 * 32 + g4 * 8]);
#pragma unroll
        for (int c = 0; c < 8; c++) {
          bf16x8 vf = *(const bf16x8*)(&Vs[(c * 16 + r16) * 64 + ((ks2 * 4 + g4) ^ rsw) * 8]);
          o[c] = __builtin_amdgcn_mfma_f32_16x16x32_bf16(pf, vf, o[c], 0, 0, 0);
        }
      }
    }

    // epilogue: O /= l, write [B,S,H,HD] bf16
    float rl[4];
#pragma unroll
    for (int r = 0; r < 4; r++) rl[r] = 1.0f / l_i[r];
#pragma unroll
    for (int c = 0; c < 8; c++) {
#pragma unroll
      for (int r = 0; r < 4; r++) {
        int rowg = t * 64 + wave * 16 + g4 * 4 + r;
        int col = c * 16 + r16;
        O[((size_t)(b * 2048 + rowg)) * 2048 + h * 128 + col] = f2bf(o[c][r] * rl[r]);
      }
    }
  }
}

// ---------------- Output projection GEMM ----------------
// out[m,d] = sum_f Attn[m,f] * Wo[d,f]. M=4096, N=2048, K=2048. fp32 output.
__global__ __launch_bounds__(256) void gemm_out(const u16* __restrict__ A,
                                                const u16* __restrict__ W,
                                                float* __restrict__ out) {
  __shared__ __align__(16) u16 As[128 * 64];
  __shared__ __align__(16) u16 Bs[128 * 64];
  const int tid = threadIdx.x;
  const int lane = tid & 63;
  const int wave = tid >> 6;
  const int wm = (wave >> 1) * 64;
  const int wn = (wave & 1) * 64;
  const int r16 = lane & 15;
  const int g4 = lane >> 4;
  const int rsw = r16 & 7;
  const int bm = blockIdx.x * 128;
  const int bn = blockIdx.y * 128;

  size_t aoff[4], boff[4];
  u16* ldsA[4];
  u16* ldsB[4];
#pragma unroll
  for (int i = 0; i < 4; i++) {
    int row = wave * 32 + i * 8 + (lane >> 3);
    int c = (lane & 7) ^ (row & 7);
    aoff[i] = (size_t)(bm + row) * 2048 + c * 8;
    boff[i] = (size_t)(bn + row) * 2048 + c * 8;
    ldsA[i] = &As[(wave * 4 + i) * 512];
    ldsB[i] = &Bs[(wave * 4 + i) * 512];
  }

  f32x4 acc[4][4];
  f32x4 zero = {0.0f, 0.0f, 0.0f, 0.0f};
#pragma unroll
  for (int m = 0; m < 4; m++)
#pragma unroll
    for (int n = 0; n < 4; n++) acc[m][n] = zero;

  for (int kt = 0; kt < 2048; kt += 64) {
    __syncthreads();
#pragma unroll
    for (int i = 0; i < 4; i++) {
      async_copy16(ldsA[i], A + aoff[i] + kt);
      async_copy16(ldsB[i], W + boff[i] + kt);
    }
    __syncthreads();
#pragma unroll
    for (int ks = 0; ks < 2; ks++) {
      bf16x8 af[4], bfr[4];
#pragma unroll
      for (int m = 0; m < 4; m++)
        af[m] = *(const bf16x8*)(&As[(wm + m * 16 + r16) * 64 + ((ks * 4 + g4) ^ rsw) * 8]);
#pragma unroll
      for (int n = 0; n < 4; n++)
        bfr[n] = *(const bf16x8*)(&Bs[(wn + n * 16 + r16) * 64 + ((ks * 4 + g4) ^ rsw) * 8]);
#pragma unroll
      for (int m = 0; m < 4; m++)
#pragma unroll
        for (int n = 0; n < 4; n++)
          acc[m][n] = __builtin_amdgcn_mfma_f32_16x16x32_bf16(af[m], bfr[n], acc[m][n], 0, 0, 0);
    }
  }

#pragma unroll
  for (int m = 0; m < 4; m++) {
#pragma unroll
    for (int n = 0; n < 4; n++) {
#pragma unroll
      for (int r = 0; r < 4; r++) {
        int row = bm + wm + m * 16 + g4 * 4 + r;
        int col = bn + wn + n * 16 + r16;
        out[(size_t)row * 2048 + col] = acc[m][n][r];
      }
    }
  }
}

extern "C" void kernel_launch(void* const* d_in, const int* in_sizes, int n_in,
                              void* d_out, int out_size, void* d_ws, size_t ws_size,
                              hipStream_t stream) {
  const float* hidden = (const float*)d_in[0];  // [2,2048,2048]
  const float* cosb   = (const float*)d_in[1];  // [2048,128]
  const float* sinb   = (const float*)d_in[2];  // [2048,128]
  const float* w_qkv  = (const float*)d_in[3];  // [3,2048,2048] -> flat [6144,2048]
  const float* w_o    = (const float*)d_in[4];  // [2048,2048]
  float* out = (float*)d_out;                   // [2,2048,2048] fp32

  char* ws = (char*)d_ws;
  u16* Xbf    = (u16*)(ws);                 // 16 MiB
  u16* Wqkvbf = (u16*)(ws + 16777216);      // 24 MiB
  u16* Wobf   = (u16*)(ws + 41943040);      // 8 MiB
  u16* Qb     = (u16*)(ws + 50331648);      // [B,H,S,HD] 16 MiB
  u16* Kb     = (u16*)(ws + 67108864);      // [B,H,S,HD] 16 MiB
  u16* Vt     = (u16*)(ws + 83886080);      // [B,H,HD,S] 16 MiB
  u16* Ob     = (u16*)(ws + 100663296);     // [B,S,H,HD] 16 MiB (end 112 MiB)

  cast_f32_bf16<<<8192, 256, 0, stream>>>(hidden, Xbf, 2097152);
  cast_f32_bf16<<<12288, 256, 0, stream>>>(w_qkv, Wqkvbf, 3145728);
  cast_f32_bf16<<<4096, 256, 0, stream>>>(w_o, Wobf, 1048576);
  gemm_qkv<<<dim3(32, 48), 256, 0, stream>>>(Xbf, Wqkvbf, Qb, Kb, Vt);
  rope_kernel<<<8192, 256, 0, stream>>>(Qb, Kb, cosb, sinb);
  flash_attn<<<dim3(16, 32), 256, 0, stream>>>(Qb, Kb, Vt, Ob);
  gemm_out<<<dim3(32, 16), 256, 0, stream>>>(Ob, Wobf, out);
}

// Round 3
// 411.061 us; speedup vs baseline: 1.3222x; 1.0834x over previous
//
#include <hip/hip_runtime.h>

typedef unsigned short u16;
typedef __bf16 bf16x8 __attribute__((ext_vector_type(8)));
typedef float f32x4 __attribute__((ext_vector_type(4)));

// Problem constants: B=2, S=2048, D=2048, H=16, HD=128, F=3*H*HD=6144, M=B*S=4096

__device__ __forceinline__ u16 f2bf(float x) {
  __bf16 h = (__bf16)x;
  return __builtin_bit_cast(u16, h);
}

// async global->LDS, 16B per lane. LDS dest must be wave-uniform; HW scatters lane i to base+16*i.
__device__ __forceinline__ void async_copy16(void* lds, const void* g) {
  __builtin_amdgcn_global_load_lds((const __attribute__((address_space(1))) void*)g,
                                   (__attribute__((address_space(3))) void*)lds, 16, 0, 0);
}

// ---------------- fused cast fp32 -> bf16 for all three tensors ----------------
__global__ __launch_bounds__(256) void cast_all(const float* __restrict__ hidden,
                                                const float* __restrict__ wqkv,
                                                const float* __restrict__ wo,
                                                u16* __restrict__ xb,
                                                u16* __restrict__ wqb,
                                                u16* __restrict__ wob) {
  int i = blockIdx.x * 256 + threadIdx.x;  // 6291456 vec4 total
  const float* s;
  u16* d;
  int off;
  if (i < 2097152) { s = hidden; d = xb; off = i; }
  else if (i < 2097152 + 3145728) { s = wqkv; d = wqb; off = i - 2097152; }
  else { s = wo; d = wob; off = i - (2097152 + 3145728); }
  float4 v = ((const float4*)s)[off];
  ushort4 o;
  o.x = f2bf(v.x); o.y = f2bf(v.y); o.z = f2bf(v.z); o.w = f2bf(v.w);
  ((ushort4*)d)[off] = o;
}

// ---------------- QKV projection GEMM + fused RoPE ----------------
// C[m,f] = sum_d X[m,d] * W[f,d]. M=4096, N=6144, K=2048. Tile 128x128, BK=64.
// Wave n-tile -> column mapping puts rope pairs (hd, hd+64) in the SAME lane:
//   col(n) = (wave&1)*32 + (n&1)*16 + (n>>1)*64 + r16   (n=0..3; col(n+2)=col(n)+64)
// Epilogue: which=blockIdx.y%3 (0=q,1=k,2=v), h=blockIdx.y/3.
// Q,K roped in-register then written [B,H,S,HD]; V written transposed [B,H,HD,S].
__global__ __launch_bounds__(256) void gemm_qkv(const u16* __restrict__ A,
                                                const u16* __restrict__ W,
                                                const float* __restrict__ cosb,
                                                const float* __restrict__ sinb,
                                                u16* __restrict__ Qb,
                                                u16* __restrict__ Kb,
                                                u16* __restrict__ Vt) {
  __shared__ __align__(16) u16 As[128 * 64];
  __shared__ __align__(16) u16 Bs[128 * 64];
  const int tid = threadIdx.x;
  const int lane = tid & 63;
  const int wave = tid >> 6;
  const int wm = (wave >> 1) * 64;
  const int r16 = lane & 15;
  const int g4 = lane >> 4;
  const int rsw = r16 & 7;
  const int bm = blockIdx.x * 128;
  const int bn = blockIdx.y * 128;

  // staging map (constant over k): issue i covers rows wave*32+i*8 .. +7
  size_t aoff[4], boff[4];
  u16* ldsA[4];
  u16* ldsB[4];
#pragma unroll
  for (int i = 0; i < 4; i++) {
    int row = wave * 32 + i * 8 + (lane >> 3);
    int c = (lane & 7) ^ (row & 7);  // global chunk feeding this lane's LDS slot
    aoff[i] = (size_t)(bm + row) * 2048 + c * 8;
    boff[i] = (size_t)(bn + row) * 2048 + c * 8;
    ldsA[i] = &As[(wave * 4 + i) * 512];
    ldsB[i] = &Bs[(wave * 4 + i) * 512];
  }

  int bcol[4];
#pragma unroll
  for (int n = 0; n < 4; n++) bcol[n] = (wave & 1) * 32 + (n & 1) * 16 + (n >> 1) * 64;

  f32x4 acc[4][4];
  f32x4 zero = {0.0f, 0.0f, 0.0f, 0.0f};
#pragma unroll
  for (int m = 0; m < 4; m++)
#pragma unroll
    for (int n = 0; n < 4; n++) acc[m][n] = zero;

  for (int kt = 0; kt < 2048; kt += 64) {
    __syncthreads();
#pragma unroll
    for (int i = 0; i < 4; i++) {
      async_copy16(ldsA[i], A + aoff[i] + kt);
      async_copy16(ldsB[i], W + boff[i] + kt);
    }
    __syncthreads();
#pragma unroll
    for (int ks = 0; ks < 2; ks++) {
      bf16x8 af[4], bfr[4];
#pragma unroll
      for (int m = 0; m < 4; m++)
        af[m] = *(const bf16x8*)(&As[(wm + m * 16 + r16) * 64 + ((ks * 4 + g4) ^ rsw) * 8]);
#pragma unroll
      for (int n = 0; n < 4; n++)
        bfr[n] = *(const bf16x8*)(&Bs[(bcol[n] + r16) * 64 + ((ks * 4 + g4) ^ rsw) * 8]);
#pragma unroll
      for (int m = 0; m < 4; m++)
#pragma unroll
        for (int n = 0; n < 4; n++)
          acc[m][n] = __builtin_amdgcn_mfma_f32_16x16x32_bf16(af[m], bfr[n], acc[m][n], 0, 0, 0);
    }
  }

  const int which = blockIdx.y % 3;
  const int hh = blockIdx.y / 3;
#pragma unroll
  for (int m = 0; m < 4; m++) {
#pragma unroll
    for (int r = 0; r < 4; r++) {
      // C/D layout (m89): col = lane&15, row = (lane>>4)*4 + r
      int row = bm + wm + m * 16 + g4 * 4 + r;  // global m index (b*S+s)
      int bb = row >> 11;
      int s = row & 2047;
      size_t bhIdx = (size_t)(bb * 16 + hh);
      if (which == 2) {
#pragma unroll
        for (int n = 0; n < 4; n++) {
          int hd = bcol[n] + r16;
          Vt[(bhIdx * 128 + hd) * 2048 + s] = f2bf(acc[m][n][r]);  // V^T: [bh][hd][s]
        }
      } else {
        u16* dst = (which ? Kb : Qb) + (bhIdx * 2048 + s) * 128;
#pragma unroll
        for (int n = 0; n < 2; n++) {
          int hd = bcol[n] + r16;  // < 64; pair is hd+64 in acc[m][n+2]
          float c = cosb[s * 128 + hd];
          float sn = sinb[s * 128 + hd];
          float x1 = acc[m][n][r], x2 = acc[m][n + 2][r];
          dst[hd] = f2bf(x1 * c - x2 * sn);
          dst[hd + 64] = f2bf(x2 * c + x1 * sn);
        }
      }
    }
  }
}

// ---------------- Flash attention (causal, online softmax, S^T layout) ----------------
// Grid (16, B*H). Block x processes q-tiles t=x and t=31-x (uniform 33 key-tiles).
// K [64][128] and V^T [128][64] double-buffered via global_load_lds (XOR-swizzled);
// prefetch for u+1 issued after the single per-iteration barrier.
// S computed TRANSPOSED (mfma(K,Q) = S^T): lane owns 16 scores of query q=lane&15,
// so row-softmax = in-lane reduce + 2 shuffles (vs 32 shuffles in natural layout).
__global__ __launch_bounds__(256) void flash_attn(const u16* __restrict__ Q,
                                                  const u16* __restrict__ K,
                                                  const u16* __restrict__ Vt,
                                                  u16* __restrict__ O) {
  __shared__ __align__(16) u16 Ks[2][64 * 128];
  __shared__ __align__(16) u16 Vs[2][128 * 64];
  __shared__ __align__(16) u16 Ps[4 * 16 * 72];  // per-wave [q][key], padded
  const int tid = threadIdx.x;
  const int lane = tid & 63;
  const int wave = tid >> 6;
  const int bh = blockIdx.y;
  const int r16 = lane & 15;
  const int g4 = lane >> 4;
  const int rsw = r16 & 7;
  const u16* Qh = Q + (size_t)bh * 2048 * 128;
  const u16* Kh = K + (size_t)bh * 2048 * 128;
  const u16* Vh = Vt + (size_t)bh * 128 * 2048;
  const int b = bh >> 4;
  const int h = bh & 15;

  // staging maps: K rows = keys (16 chunks/row), V rows = hd (8 chunks/row)
  size_t koff[4], voff[4];
  int ldsOff[4];
#pragma unroll
  for (int i = 0; i < 4; i++) {
    int kr = (wave * 4 + i) * 4 + (lane >> 4);  // 0..63
    int kc = (lane & 15) ^ (kr & 7);
    koff[i] = (size_t)kr * 128 + kc * 8;
    int vr = (wave * 4 + i) * 8 + (lane >> 3);  // 0..127
    int vc = (lane & 7) ^ (vr & 7);
    voff[i] = (size_t)vr * 2048 + vc * 8;
    ldsOff[i] = (wave * 4 + i) * 512;
  }

  const float sc = 0.08838834764831845f * 1.4426950408889634f;  // 1/sqrt(128) * log2(e)

#pragma unroll 1
  for (int pass = 0; pass < 2; pass++) {
    const int t = pass == 0 ? (int)blockIdx.x : 31 - (int)blockIdx.x;

    // Q fragments (B-operand now; same lane layout: q=lane&15, k=(lane>>4)*8+j)
    bf16x8 qf[4];
    {
      int qrow = t * 64 + wave * 16 + r16;
#pragma unroll
      for (int ks = 0; ks < 4; ks++)
        qf[ks] = *(const bf16x8*)(Qh + (size_t)qrow * 128 + ks * 32 + g4 * 8);
    }

    f32x4 o[8];
    f32x4 zero = {0.0f, 0.0f, 0.0f, 0.0f};
#pragma unroll
    for (int c = 0; c < 8; c++) o[c] = zero;
    float m_i = -__builtin_inff();  // state for query q = wave*16 + r16 (4 copies across g4)
    float l_i = 0.0f;

    __syncthreads();  // previous pass / iteration done before overwriting buf 0
#pragma unroll
    for (int i = 0; i < 4; i++) {  // prologue: stage u=0 into buf 0
      async_copy16(&Ks[0][ldsOff[i]], Kh + koff[i]);
      async_copy16(&Vs[0][ldsOff[i]], Vh + voff[i]);
    }

    int cur = 0;
    for (int u = 0; u <= t; u++) {
      __syncthreads();  // drains staging of buf[cur]; all waves done with buf[cur^1]
      if (u < t) {      // prefetch u+1 into the other buffer; in flight during compute
#pragma unroll
        for (int i = 0; i < 4; i++) {
          async_copy16(&Ks[cur ^ 1][ldsOff[i]], Kh + (size_t)(u + 1) * 64 * 128 + koff[i]);
          async_copy16(&Vs[cur ^ 1][ldsOff[i]], Vh + (size_t)(u + 1) * 64 + voff[i]);
        }
      }

      // S^T = K Q^T : tile n covers keys 16n..16n+15. A-frag = K rows, B-frag = Q.
      f32x4 sacc[4];
#pragma unroll
      for (int n = 0; n < 4; n++) sacc[n] = zero;
#pragma unroll
      for (int n = 0; n < 4; n++) {
#pragma unroll
        for (int ks = 0; ks < 4; ks++) {
          bf16x8 kf = *(const bf16x8*)(&Ks[cur][(n * 16 + r16) * 128 + ((ks * 4 + g4) ^ rsw) * 8]);
          sacc[n] = __builtin_amdgcn_mfma_f32_16x16x32_bf16(kf, qf[ks], sacc[n], 0, 0, 0);
        }
      }

      // lane view: q = wave*16 + r16; keys = u*64 + 16n + g4*4 + r  (16 values)
      const int qg = t * 64 + wave * 16 + r16;
      float e[4][4];
      float vmax = -__builtin_inff();
#pragma unroll
      for (int n = 0; n < 4; n++)
#pragma unroll
        for (int r = 0; r < 4; r++) {
          float ev = sacc[n][r] * sc;
          if (u == t) {
            int key = u * 64 + 16 * n + g4 * 4 + r;
            if (key > qg) ev = -__builtin_inff();
          }
          e[n][r] = ev;
          vmax = fmaxf(vmax, ev);
        }
      vmax = fmaxf(vmax, __shfl_xor(vmax, 16));
      vmax = fmaxf(vmax, __shfl_xor(vmax, 32));
      float mn = fmaxf(m_i, vmax);
      float alpha = exp2f(m_i - mn);
      m_i = mn;
      float ssum = 0.0f;
      u16* Pw = &Ps[wave * 16 * 72];
#pragma unroll
      for (int n = 0; n < 4; n++)
#pragma unroll
        for (int r = 0; r < 4; r++) {
          float pv = exp2f(e[n][r] - mn);
          ssum += pv;
          Pw[r16 * 72 + 16 * n + g4 * 4 + r] = f2bf(pv);  // P[q][key]
        }
      ssum += __shfl_xor(ssum, 16);
      ssum += __shfl_xor(ssum, 32);
      l_i = l_i * alpha + ssum;

      // broadcast alpha to O-layout rows (q' = g4*4+r): lane q' holds alpha for q=q'
      float alpha_o[4];
#pragma unroll
      for (int r = 0; r < 4; r++) alpha_o[r] = __shfl(alpha, g4 * 4 + r);
#pragma unroll
      for (int c = 0; c < 8; c++)
#pragma unroll
        for (int r = 0; r < 4; r++) o[c][r] *= alpha_o[r];

      // PV: O[16q x 128hd] += P[16q x 64k] * V^T[...]
#pragma unroll
      for (int ks2 = 0; ks2 < 2; ks2++) {
        bf16x8 pf = *(const bf16x8*)(&Pw[r16 * 72 + ks2 * 32 + g4 * 8]);
#pragma unroll
        for (int c = 0; c < 8; c++) {
          bf16x8 vf = *(const bf16x8*)(&Vs[cur][(c * 16 + r16) * 64 + ((ks2 * 4 + g4) ^ rsw) * 8]);
          o[c] = __builtin_amdgcn_mfma_f32_16x16x32_bf16(pf, vf, o[c], 0, 0, 0);
        }
      }
      cur ^= 1;
    }

    // epilogue: O /= l (l for row q'=g4*4+r lives in lane q'), write [B,S,H,HD] bf16
    float rl[4];
#pragma unroll
    for (int r = 0; r < 4; r++) rl[r] = 1.0f / __shfl(l_i, g4 * 4 + r);
#pragma unroll
    for (int c = 0; c < 8; c++) {
#pragma unroll
      for (int r = 0; r < 4; r++) {
        int rowg = t * 64 + wave * 16 + g4 * 4 + r;
        int col = c * 16 + r16;
        O[((size_t)(b * 2048 + rowg)) * 2048 + h * 128 + col] = f2bf(o[c][r] * rl[r]);
      }
    }
  }
}

// ---------------- Output projection GEMM ----------------
// out[m,d] = sum_f Attn[m,f] * Wo[d,f]. M=4096, N=2048, K=2048. fp32 output.
__global__ __launch_bounds__(256) void gemm_out(const u16* __restrict__ A,
                                                const u16* __restrict__ W,
                                                float* __restrict__ out) {
  __shared__ __align__(16) u16 As[128 * 64];
  __shared__ __align__(16) u16 Bs[128 * 64];
  const int tid = threadIdx.x;
  const int lane = tid & 63;
  const int wave = tid >> 6;
  const int wm = (wave >> 1) * 64;
  const int wn = (wave & 1) * 64;
  const int r16 = lane & 15;
  const int g4 = lane >> 4;
  const int rsw = r16 & 7;
  const int bm = blockIdx.x * 128;
  const int bn = blockIdx.y * 128;

  size_t aoff[4], boff[4];
  u16* ldsA[4];
  u16* ldsB[4];
#pragma unroll
  for (int i = 0; i < 4; i++) {
    int row = wave * 32 + i * 8 + (lane >> 3);
    int c = (lane & 7) ^ (row & 7);
    aoff[i] = (size_t)(bm + row) * 2048 + c * 8;
    boff[i] = (size_t)(bn + row) * 2048 + c * 8;
    ldsA[i] = &As[(wave * 4 + i) * 512];
    ldsB[i] = &Bs[(wave * 4 + i) * 512];
  }

  f32x4 acc[4][4];
  f32x4 zero = {0.0f, 0.0f, 0.0f, 0.0f};
#pragma unroll
  for (int m = 0; m < 4; m++)
#pragma unroll
    for (int n = 0; n < 4; n++) acc[m][n] = zero;

  for (int kt = 0; kt < 2048; kt += 64) {
    __syncthreads();
#pragma unroll
    for (int i = 0; i < 4; i++) {
      async_copy16(ldsA[i], A + aoff[i] + kt);
      async_copy16(ldsB[i], W + boff[i] + kt);
    }
    __syncthreads();
#pragma unroll
    for (int ks = 0; ks < 2; ks++) {
      bf16x8 af[4], bfr[4];
#pragma unroll
      for (int m = 0; m < 4; m++)
        af[m] = *(const bf16x8*)(&As[(wm + m * 16 + r16) * 64 + ((ks * 4 + g4) ^ rsw) * 8]);
#pragma unroll
      for (int n = 0; n < 4; n++)
        bfr[n] = *(const bf16x8*)(&Bs[(wn + n * 16 + r16) * 64 + ((ks * 4 + g4) ^ rsw) * 8]);
#pragma unroll
      for (int m = 0; m < 4; m++)
#pragma unroll
        for (int n = 0; n < 4; n++)
          acc[m][n] = __builtin_amdgcn_mfma_f32_16x16x32_bf16(af[m], bfr[n], acc[m][n], 0, 0, 0);
    }
  }

#pragma unroll
  for (int m = 0; m < 4; m++) {
#pragma unroll
    for (int n = 0; n < 4; n++) {
#pragma unroll
      for (int r = 0; r < 4; r++) {
        int row = bm + wm + m * 16 + g4 * 4 + r;
        int col = bn + wn + n * 16 + r16;
        out[(size_t)row * 2048 + col] = acc[m][n][r];
      }
    }
  }
}

extern "C" void kernel_launch(void* const* d_in, const int* in_sizes, int n_in,
                              void* d_out, int out_size, void* d_ws, size_t ws_size,
                              hipStream_t stream) {
  const float* hidden = (const float*)d_in[0];  // [2,2048,2048]
  const float* cosb   = (const float*)d_in[1];  // [2048,128]
  const float* sinb   = (const float*)d_in[2];  // [2048,128]
  const float* w_qkv  = (const float*)d_in[3];  // [3,2048,2048] -> flat [6144,2048]
  const float* w_o    = (const float*)d_in[4];  // [2048,2048]
  float* out = (float*)d_out;                   // [2,2048,2048] fp32

  char* ws = (char*)d_ws;
  u16* Xbf    = (u16*)(ws);                 // 16 MiB
  u16* Wqkvbf = (u16*)(ws + 16777216);      // 24 MiB
  u16* Wobf   = (u16*)(ws + 41943040);      // 8 MiB
  u16* Qb     = (u16*)(ws + 50331648);      // [B,H,S,HD] 16 MiB
  u16* Kb     = (u16*)(ws + 67108864);      // [B,H,S,HD] 16 MiB
  u16* Vt     = (u16*)(ws + 83886080);      // [B,H,HD,S] 16 MiB
  u16* Ob     = (u16*)(ws + 100663296);     // [B,S,H,HD] 16 MiB (end 112 MiB)

  cast_all<<<24576, 256, 0, stream>>>(hidden, w_qkv, w_o, Xbf, Wqkvbf, Wobf);
  gemm_qkv<<<dim3(32, 48), 256, 0, stream>>>(Xbf, Wqkvbf, cosb, sinb, Qb, Kb, Vt);
  flash_attn<<<dim3(16, 32), 256, 0, stream>>>(Qb, Kb, Vt, Ob);
  gemm_out<<<dim3(32, 16), 256, 0, stream>>>(Ob, Wobf, out);
}

// Round 4
// 409.636 us; speedup vs baseline: 1.3268x; 1.0035x over previous
//
#include <hip/hip_runtime.h>

typedef unsigned short u16;
typedef __bf16 bf16x8 __attribute__((ext_vector_type(8)));
typedef float f32x4 __attribute__((ext_vector_type(4)));

// Problem constants: B=2, S=2048, D=2048, H=16, HD=128, F=3*H*HD=6144, M=B*S=4096

__device__ __forceinline__ u16 f2bf(float x) {
  __bf16 h = (__bf16)x;
  return __builtin_bit_cast(u16, h);
}

// async global->LDS, 16B per lane. LDS dest must be wave-uniform; HW scatters lane i to base+16*i.
__device__ __forceinline__ void async_copy16(void* lds, const void* g) {
  __builtin_amdgcn_global_load_lds((const __attribute__((address_space(1))) void*)g,
                                   (__attribute__((address_space(3))) void*)lds, 16, 0, 0);
}

// ---------------- fused cast fp32 -> bf16 for all three tensors ----------------
__global__ __launch_bounds__(256) void cast_all(const float* __restrict__ hidden,
                                                const float* __restrict__ wqkv,
                                                const float* __restrict__ wo,
                                                u16* __restrict__ xb,
                                                u16* __restrict__ wqb,
                                                u16* __restrict__ wob) {
  int i = blockIdx.x * 256 + threadIdx.x;  // 6291456 vec4 total
  const float* s;
  u16* d;
  int off;
  if (i < 2097152) { s = hidden; d = xb; off = i; }
  else if (i < 2097152 + 3145728) { s = wqkv; d = wqb; off = i - 2097152; }
  else { s = wo; d = wob; off = i - (2097152 + 3145728); }
  float4 v = ((const float4*)s)[off];
  ushort4 o;
  o.x = f2bf(v.x); o.y = f2bf(v.y); o.z = f2bf(v.z); o.w = f2bf(v.w);
  ((ushort4*)d)[off] = o;
}

// ---------------- QKV projection GEMM + fused RoPE (+ softmax scale folded into Q) ----
// C[m,f] = sum_d X[m,d] * W[f,d]. M=4096, N=6144, K=2048. Tile 128x128, BK=64.
// Wave n-tile -> column mapping puts rope pairs (hd, hd+64) in the SAME lane:
//   col(n) = (wave&1)*32 + (n&1)*16 + (n>>1)*64 + r16   (n=0..3; col(n+2)=col(n)+64)
// Q additionally scaled by 1/sqrt(HD)*log2(e) so flash uses exp2 directly.
__global__ __launch_bounds__(256) void gemm_qkv(const u16* __restrict__ A,
                                                const u16* __restrict__ W,
                                                const float* __restrict__ cosb,
                                                const float* __restrict__ sinb,
                                                u16* __restrict__ Qb,
                                                u16* __restrict__ Kb,
                                                u16* __restrict__ Vt) {
  __shared__ __align__(16) u16 As[128 * 64];
  __shared__ __align__(16) u16 Bs[128 * 64];
  const int tid = threadIdx.x;
  const int lane = tid & 63;
  const int wave = tid >> 6;
  const int wm = (wave >> 1) * 64;
  const int r16 = lane & 15;
  const int g4 = lane >> 4;
  const int rsw = r16 & 7;
  const int bm = blockIdx.x * 128;
  const int bn = blockIdx.y * 128;

  // staging map (constant over k): issue i covers rows wave*32+i*8 .. +7
  size_t aoff[4], boff[4];
  u16* ldsA[4];
  u16* ldsB[4];
#pragma unroll
  for (int i = 0; i < 4; i++) {
    int row = wave * 32 + i * 8 + (lane >> 3);
    int c = (lane & 7) ^ (row & 7);  // global chunk feeding this lane's LDS slot
    aoff[i] = (size_t)(bm + row) * 2048 + c * 8;
    boff[i] = (size_t)(bn + row) * 2048 + c * 8;
    ldsA[i] = &As[(wave * 4 + i) * 512];
    ldsB[i] = &Bs[(wave * 4 + i) * 512];
  }

  int bcol[4];
#pragma unroll
  for (int n = 0; n < 4; n++) bcol[n] = (wave & 1) * 32 + (n & 1) * 16 + (n >> 1) * 64;

  f32x4 acc[4][4];
  f32x4 zero = {0.0f, 0.0f, 0.0f, 0.0f};
#pragma unroll
  for (int m = 0; m < 4; m++)
#pragma unroll
    for (int n = 0; n < 4; n++) acc[m][n] = zero;

  for (int kt = 0; kt < 2048; kt += 64) {
    __syncthreads();
#pragma unroll
    for (int i = 0; i < 4; i++) {
      async_copy16(ldsA[i], A + aoff[i] + kt);
      async_copy16(ldsB[i], W + boff[i] + kt);
    }
    __syncthreads();
#pragma unroll
    for (int ks = 0; ks < 2; ks++) {
      bf16x8 af[4], bfr[4];
#pragma unroll
      for (int m = 0; m < 4; m++)
        af[m] = *(const bf16x8*)(&As[(wm + m * 16 + r16) * 64 + ((ks * 4 + g4) ^ rsw) * 8]);
#pragma unroll
      for (int n = 0; n < 4; n++)
        bfr[n] = *(const bf16x8*)(&Bs[(bcol[n] + r16) * 64 + ((ks * 4 + g4) ^ rsw) * 8]);
#pragma unroll
      for (int m = 0; m < 4; m++)
#pragma unroll
        for (int n = 0; n < 4; n++)
          acc[m][n] = __builtin_amdgcn_mfma_f32_16x16x32_bf16(af[m], bfr[n], acc[m][n], 0, 0, 0);
    }
  }

  const int which = blockIdx.y % 3;
  const int hh = blockIdx.y / 3;
  // Q gets 1/sqrt(128)*log2(e) folded in so flash's softmax is pure exp2
  const float qs = (which == 0) ? 0.08838834764831845f * 1.4426950408889634f : 1.0f;
#pragma unroll
  for (int m = 0; m < 4; m++) {
#pragma unroll
    for (int r = 0; r < 4; r++) {
      // C/D layout (m89): col = lane&15, row = (lane>>4)*4 + r
      int row = bm + wm + m * 16 + g4 * 4 + r;  // global m index (b*S+s)
      int bb = row >> 11;
      int s = row & 2047;
      size_t bhIdx = (size_t)(bb * 16 + hh);
      if (which == 2) {
#pragma unroll
        for (int n = 0; n < 4; n++) {
          int hd = bcol[n] + r16;
          Vt[(bhIdx * 128 + hd) * 2048 + s] = f2bf(acc[m][n][r]);  // V^T: [bh][hd][s]
        }
      } else {
        u16* dst = (which ? Kb : Qb) + (bhIdx * 2048 + s) * 128;
#pragma unroll
        for (int n = 0; n < 2; n++) {
          int hd = bcol[n] + r16;  // < 64; pair is hd+64 in acc[m][n+2]
          float c = cosb[s * 128 + hd] * qs;
          float sn = sinb[s * 128 + hd] * qs;
          float x1 = acc[m][n][r], x2 = acc[m][n + 2][r];
          dst[hd] = f2bf(x1 * c - x2 * sn);
          dst[hd + 64] = f2bf(x2 * c + x1 * sn);
        }
      }
    }
  }
}

// ---------------- Flash attention (causal, online softmax, S^T + O^T layouts) --------
// Grid (16, B*H). Block x processes q-tiles t=x and t=31-x (uniform 33 key-tiles).
// K [64][128] and V^T [128][64] double-buffered via global_load_lds (XOR-swizzled);
// prefetch for u+1 issued after the single per-iteration barrier.
// S^T = mfma(K, Q): lane owns scores of query q=lane&15 -> softmax state lane-local.
// O^T = mfma(V^T, P): C/D col = q = lane&15 -> alpha/l rescale is lane-local too
// (no shuffles anywhere in the softmax/rescale path).
__global__ __launch_bounds__(256) void flash_attn(const u16* __restrict__ Q,
                                                  const u16* __restrict__ K,
                                                  const u16* __restrict__ Vt,
                                                  u16* __restrict__ O) {
  __shared__ __align__(16) u16 Ks[2][64 * 128];
  __shared__ __align__(16) u16 Vs[2][128 * 64];
  __shared__ __align__(16) u16 Ps[4 * 16 * 72];  // per-wave [q][key], padded
  const int tid = threadIdx.x;
  const int lane = tid & 63;
  const int wave = tid >> 6;
  const int bh = blockIdx.y;
  const int r16 = lane & 15;
  const int g4 = lane >> 4;
  const int rsw = r16 & 7;
  const u16* Qh = Q + (size_t)bh * 2048 * 128;
  const u16* Kh = K + (size_t)bh * 2048 * 128;
  const u16* Vh = Vt + (size_t)bh * 128 * 2048;
  const int b = bh >> 4;
  const int h = bh & 15;

  // staging maps: K rows = keys (16 chunks/row), V rows = hd (8 chunks/row)
  size_t koff[4], voff[4];
  int ldsOff[4];
#pragma unroll
  for (int i = 0; i < 4; i++) {
    int kr = (wave * 4 + i) * 4 + (lane >> 4);  // 0..63
    int kc = (lane & 15) ^ (kr & 7);
    koff[i] = (size_t)kr * 128 + kc * 8;
    int vr = (wave * 4 + i) * 8 + (lane >> 3);  // 0..127
    int vc = (lane & 7) ^ (vr & 7);
    voff[i] = (size_t)vr * 2048 + vc * 8;
    ldsOff[i] = (wave * 4 + i) * 512;
  }

#pragma unroll 1
  for (int pass = 0; pass < 2; pass++) {
    const int t = pass == 0 ? (int)blockIdx.x : 31 - (int)blockIdx.x;

    // Q fragments (B-operand of S^T; lane layout: q=lane&15, k=(lane>>4)*8+j)
    bf16x8 qf[4];
    {
      int qrow = t * 64 + wave * 16 + r16;
#pragma unroll
      for (int ks = 0; ks < 4; ks++)
        qf[ks] = *(const bf16x8*)(Qh + (size_t)qrow * 128 + ks * 32 + g4 * 8);
    }

    f32x4 o[8];  // O^T: tile c = hd 16c..16c+15; col=q=r16, row=hd=g4*4+r
    f32x4 zero = {0.0f, 0.0f, 0.0f, 0.0f};
#pragma unroll
    for (int c = 0; c < 8; c++) o[c] = zero;
    float m_i = -__builtin_inff();  // state for query q = wave*16 + r16
    float l_i = 0.0f;

    __syncthreads();  // previous pass/iteration done before overwriting buf 0
#pragma unroll
    for (int i = 0; i < 4; i++) {  // prologue: stage u=0 into buf 0
      async_copy16(&Ks[0][ldsOff[i]], Kh + koff[i]);
      async_copy16(&Vs[0][ldsOff[i]], Vh + voff[i]);
    }

    int cur = 0;
    for (int u = 0; u <= t; u++) {
      __syncthreads();  // drains staging of buf[cur]; all waves done with buf[cur^1]
      if (u < t) {      // prefetch u+1 into the other buffer; in flight during compute
#pragma unroll
        for (int i = 0; i < 4; i++) {
          async_copy16(&Ks[cur ^ 1][ldsOff[i]], Kh + (size_t)(u + 1) * 64 * 128 + koff[i]);
          async_copy16(&Vs[cur ^ 1][ldsOff[i]], Vh + (size_t)(u + 1) * 64 + voff[i]);
        }
      }

      // S^T = K Q^T : tile n covers keys 16n..16n+15. A-frag = K rows, B-frag = Q.
      f32x4 sacc[4];
#pragma unroll
      for (int n = 0; n < 4; n++) sacc[n] = zero;
#pragma unroll
      for (int n = 0; n < 4; n++) {
#pragma unroll
        for (int ks = 0; ks < 4; ks++) {
          bf16x8 kf = *(const bf16x8*)(&Ks[cur][(n * 16 + r16) * 128 + ((ks * 4 + g4) ^ rsw) * 8]);
          sacc[n] = __builtin_amdgcn_mfma_f32_16x16x32_bf16(kf, qf[ks], sacc[n], 0, 0, 0);
        }
      }

      // lane view: q = wave*16 + r16; keys = u*64 + 16n + g4*4 + r. Scale pre-folded into Q.
      const int qg = t * 64 + wave * 16 + r16;
      float e[4][4];
      float vmax = -__builtin_inff();
#pragma unroll
      for (int n = 0; n < 4; n++)
#pragma unroll
        for (int r = 0; r < 4; r++) {
          float ev = sacc[n][r];
          if (u == t) {
            int key = u * 64 + 16 * n + g4 * 4 + r;
            if (key > qg) ev = -__builtin_inff();
          }
          e[n][r] = ev;
          vmax = fmaxf(vmax, ev);
        }
      vmax = fmaxf(vmax, __shfl_xor(vmax, 16));
      vmax = fmaxf(vmax, __shfl_xor(vmax, 32));
      float mn = fmaxf(m_i, vmax);
      float alpha = exp2f(m_i - mn);
      m_i = mn;
      float ssum = 0.0f;
      u16* Pw = &Ps[wave * 16 * 72];
#pragma unroll
      for (int n = 0; n < 4; n++) {
        ushort4 pk;
        float p0 = exp2f(e[n][0] - mn);
        float p1 = exp2f(e[n][1] - mn);
        float p2 = exp2f(e[n][2] - mn);
        float p3 = exp2f(e[n][3] - mn);
        ssum += (p0 + p1) + (p2 + p3);
        pk.x = f2bf(p0); pk.y = f2bf(p1); pk.z = f2bf(p2); pk.w = f2bf(p3);
        *(ushort4*)(&Pw[r16 * 72 + 16 * n + g4 * 4]) = pk;  // P[q][key], 8B packed
      }
      ssum += __shfl_xor(ssum, 16);
      ssum += __shfl_xor(ssum, 32);
      l_i = l_i * alpha + ssum;

      // O^T rescale: col = q = lane&15 -> alpha is lane-local, no broadcast
#pragma unroll
      for (int c = 0; c < 8; c++)
#pragma unroll
        for (int r = 0; r < 4; r++) o[c][r] *= alpha;

      // O^T += V^T * P : A-frag = V^T rows (hd), B-frag = P cols (q)
#pragma unroll
      for (int ks2 = 0; ks2 < 2; ks2++) {
        bf16x8 pf = *(const bf16x8*)(&Pw[r16 * 72 + ks2 * 32 + g4 * 8]);
#pragma unroll
        for (int c = 0; c < 8; c++) {
          bf16x8 vf = *(const bf16x8*)(&Vs[cur][(c * 16 + r16) * 64 + ((ks2 * 4 + g4) ^ rsw) * 8]);
          o[c] = __builtin_amdgcn_mfma_f32_16x16x32_bf16(vf, pf, o[c], 0, 0, 0);
        }
      }
      cur ^= 1;
    }

    // epilogue: O^T /= l (lane-local), write [B,S,H,HD] bf16 as packed 8B stores
    float rl = 1.0f / l_i;
    int srow = t * 64 + wave * 16 + r16;
    u16* dst = O + ((size_t)(b * 2048 + srow)) * 2048 + h * 128;
#pragma unroll
    for (int c = 0; c < 8; c++) {
      ushort4 pk;
      pk.x = f2bf(o[c][0] * rl);
      pk.y = f2bf(o[c][1] * rl);
      pk.z = f2bf(o[c][2] * rl);
      pk.w = f2bf(o[c][3] * rl);
      *(ushort4*)(dst + c * 16 + g4 * 4) = pk;
    }
  }
}

// ---------------- Output projection GEMM ----------------
// out[m,d] = sum_f Attn[m,f] * Wo[d,f]. M=4096, N=2048, K=2048. fp32 output.
__global__ __launch_bounds__(256) void gemm_out(const u16* __restrict__ A,
                                                const u16* __restrict__ W,
                                                float* __restrict__ out) {
  __shared__ __align__(16) u16 As[128 * 64];
  __shared__ __align__(16) u16 Bs[128 * 64];
  const int tid = threadIdx.x;
  const int lane = tid & 63;
  const int wave = tid >> 6;
  const int wm = (wave >> 1) * 64;
  const int wn = (wave & 1) * 64;
  const int r16 = lane & 15;
  const int g4 = lane >> 4;
  const int rsw = r16 & 7;
  const int bm = blockIdx.x * 128;
  const int bn = blockIdx.y * 128;

  size_t aoff[4], boff[4];
  u16* ldsA[4];
  u16* ldsB[4];
#pragma unroll
  for (int i = 0; i < 4; i++) {
    int row = wave * 32 + i * 8 + (lane >> 3);
    int c = (lane & 7) ^ (row & 7);
    aoff[i] = (size_t)(bm + row) * 2048 + c * 8;
    boff[i] = (size_t)(bn + row) * 2048 + c * 8;
    ldsA[i] = &As[(wave * 4 + i) * 512];
    ldsB[i] = &Bs[(wave * 4 + i) * 512];
  }

  f32x4 acc[4][4];
  f32x4 zero = {0.0f, 0.0f, 0.0f, 0.0f};
#pragma unroll
  for (int m = 0; m < 4; m++)
#pragma unroll
    for (int n = 0; n < 4; n++) acc[m][n] = zero;

  for (int kt = 0; kt < 2048; kt += 64) {
    __syncthreads();
#pragma unroll
    for (int i = 0; i < 4; i++) {
      async_copy16(ldsA[i], A + aoff[i] + kt);
      async_copy16(ldsB[i], W + boff[i] + kt);
    }
    __syncthreads();
#pragma unroll
    for (int ks = 0; ks < 2; ks++) {
      bf16x8 af[4], bfr[4];
#pragma unroll
      for (int m = 0; m < 4; m++)
        af[m] = *(const bf16x8*)(&As[(wm + m * 16 + r16) * 64 + ((ks * 4 + g4) ^ rsw) * 8]);
#pragma unroll
      for (int n = 0; n < 4; n++)
        bfr[n] = *(const bf16x8*)(&Bs[(wn + n * 16 + r16) * 64 + ((ks * 4 + g4) ^ rsw) * 8]);
#pragma unroll
      for (int m = 0; m < 4; m++)
#pragma unroll
        for (int n = 0; n < 4; n++)
          acc[m][n] = __builtin_amdgcn_mfma_f32_16x16x32_bf16(af[m], bfr[n], acc[m][n], 0, 0, 0);
    }
  }

#pragma unroll
  for (int m = 0; m < 4; m++) {
#pragma unroll
    for (int n = 0; n < 4; n++) {
#pragma unroll
      for (int r = 0; r < 4; r++) {
        int row = bm + wm + m * 16 + g4 * 4 + r;
        int col = bn + wn + n * 16 + r16;
        out[(size_t)row * 2048 + col] = acc[m][n][r];
      }
    }
  }
}

extern "C" void kernel_launch(void* const* d_in, const int* in_sizes, int n_in,
                              void* d_out, int out_size, void* d_ws, size_t ws_size,
                              hipStream_t stream) {
  const float* hidden = (const float*)d_in[0];  // [2,2048,2048]
  const float* cosb   = (const float*)d_in[1];  // [2048,128]
  const float* sinb   = (const float*)d_in[2];  // [2048,128]
  const float* w_qkv  = (const float*)d_in[3];  // [3,2048,2048] -> flat [6144,2048]
  const float* w_o    = (const float*)d_in[4];  // [2048,2048]
  float* out = (float*)d_out;                   // [2,2048,2048] fp32

  char* ws = (char*)d_ws;
  u16* Xbf    = (u16*)(ws);                 // 16 MiB
  u16* Wqkvbf = (u16*)(ws + 16777216);      // 24 MiB
  u16* Wobf   = (u16*)(ws + 41943040);      // 8 MiB
  u16* Qb     = (u16*)(ws + 50331648);      // [B,H,S,HD] 16 MiB
  u16* Kb     = (u16*)(ws + 67108864);      // [B,H,S,HD] 16 MiB
  u16* Vt     = (u16*)(ws + 83886080);      // [B,H,HD,S] 16 MiB
  u16* Ob     = (u16*)(ws + 100663296);     // [B,S,H,HD] 16 MiB (end 112 MiB)

  cast_all<<<24576, 256, 0, stream>>>(hidden, w_qkv, w_o, Xbf, Wqkvbf, Wobf);
  gemm_qkv<<<dim3(32, 48), 256, 0, stream>>>(Xbf, Wqkvbf, cosb, sinb, Qb, Kb, Vt);
  flash_attn<<<dim3(16, 32), 256, 0, stream>>>(Qb, Kb, Vt, Ob);
  gemm_out<<<dim3(32, 16), 256, 0, stream>>>(Ob, Wobf, out);
}